// Round 2
// baseline (529.877 us; speedup 1.0000x reference)
//
#include <hip/hip_runtime.h>
#include <hip/hip_bf16.h>
#include <stdint.h>

using bf16   = __hip_bfloat16;
using short8 = __attribute__((ext_vector_type(8))) short;
using f32x4  = __attribute__((ext_vector_type(4))) float;

#define MFMA_BF16(a, b, c) __builtin_amdgcn_mfma_f32_16x16x32_bf16((a), (b), (c), 0, 0, 0)

static constexpr int   kB = 2, kN = 2048, kD = 1024, kH = 16, kHd = 64;
static constexpr float kAlpha = 1.0f;

__device__ __forceinline__ short f2bfbits(float x) {
  bf16 h = __float2bfloat16(x);
  return __builtin_bit_cast(short, h);
}
__device__ __forceinline__ float bfbits2f(short s) {
  unsigned u = ((unsigned)(unsigned short)s) << 16;
  return __builtin_bit_cast(float, u);
}

// ---------- fp32 -> bf16 contiguous convert ----------
__global__ void k_convert(const float* __restrict__ in, bf16* __restrict__ out, int n4) {
  int i = blockIdx.x * 256 + threadIdx.x;
  if (i >= n4) return;
  float4 v = *(const float4*)(in + (size_t)i * 4);
  ushort4 u;
  u.x = (unsigned short)f2bfbits(v.x);
  u.y = (unsigned short)f2bfbits(v.y);
  u.z = (unsigned short)f2bfbits(v.z);
  u.w = (unsigned short)f2bfbits(v.w);
  *(ushort4*)(out + (size_t)i * 4) = u;
}

// ---------- W[K][N] fp32 -> Wt[N][K] bf16 (LDS tile transpose) ----------
__global__ void k_transpose(const float* __restrict__ W, bf16* __restrict__ Wt, int K, int N) {
  __shared__ float tile[32][33];
  int bk = blockIdx.y * 32, bn = blockIdx.x * 32;
  int tx = threadIdx.x & 31, ty = threadIdx.x >> 5;  // ty 0..7
#pragma unroll
  for (int i = 0; i < 4; ++i)
    tile[ty + i * 8][tx] = W[(size_t)(bk + ty + i * 8) * N + bn + tx];
  __syncthreads();
#pragma unroll
  for (int i = 0; i < 4; ++i)
    Wt[(size_t)(bn + ty + i * 8) * K + bk + tx] = __float2bfloat16(tile[tx][ty + i * 8]);
}

// ---------- per-(b,d) sum |x| over tokens (atomic partials) ----------
__global__ void k_colsum(const float* __restrict__ x, float* __restrict__ colsum) {
  int b = blockIdx.z;
  int d = blockIdx.x * 256 + threadIdx.x;
  int n0 = blockIdx.y * 256;
  const float* px = x + ((size_t)b * kN + n0) * kD + d;
  float s = 0.f;
  for (int n = 0; n < 256; ++n) s += fabsf(px[(size_t)n * kD]);
  atomicAdd(&colsum[b * kD + d], s);
}

// ---------- sum q^2 per (b,h) ----------
__global__ void k_froq(const bf16* __restrict__ q, float* __restrict__ froqsq) {
  int bh = blockIdx.x;
  const short* p = (const short*)(q + (size_t)bh * kN * kHd);
  float s = 0.f;
  for (int i = threadIdx.x; i < kN * kHd / 8; i += 256) {
    short8 v = *(const short8*)(p + (size_t)i * 8);
#pragma unroll
    for (int j = 0; j < 8; ++j) { float f = bfbits2f(v[j]); s += f * f; }
  }
#pragma unroll
  for (int off = 32; off >= 1; off >>= 1) s += __shfl_down(s, off);
  __shared__ float red[4];
  if ((threadIdx.x & 63) == 0) red[threadIdx.x >> 6] = s;
  __syncthreads();
  if (threadIdx.x == 0) froqsq[bh] = red[0] + red[1] + red[2] + red[3];
}

// ---------- scale[b,h] = 2*alpha / (sqrt(froq_sq) * max_d colsum) ----------
__global__ void k_scale(const float* __restrict__ colsum, const float* __restrict__ froqsq,
                        float* __restrict__ scale) {
  int t = threadIdx.x;  // 32 threads = B*H
  int b = t >> 4;
  float mx = 0.f;
  for (int d = 0; d < kD; ++d) mx = fmaxf(mx, colsum[b * kD + d]);
  scale[t] = 2.0f * kAlpha / (sqrtf(froqsq[t]) * mx);
}

// ---------- bf16 GEMM: C[M][Nout] = A[M][K] @ Bt[Nout][K]^T + bias ----------
// 128x128 tile, BK=32, 4 waves (2x2), each wave 64x64 = 4x4 16x16 frags.
// LDS slot-XOR swizzle: chunk (row, s) holds k-slot hi = s ^ ((row>>1)&3)  -> 2-way (free) banks.
// EPI 0: scatter to q/k (row-major [BH][N][hd]) and vT ([BH][hd][N]); EPI 1: fp32 out.
template <int EPI>
__global__ __launch_bounds__(256) void k_gemm(
    const bf16* __restrict__ A, const bf16* __restrict__ Bt,
    const float* __restrict__ bias, int K, int Nout,
    bf16* __restrict__ q, bf16* __restrict__ kk, bf16* __restrict__ vT,
    float* __restrict__ out) {
  __shared__ short8 AsV[512], BsV[512];
  short* As = (short*)AsV;
  short* Bs = (short*)BsV;
  const int tid = threadIdx.x;
  const int lane = tid & 63, wid = tid >> 6;
  const int hi = lane >> 4, lo = lane & 15;
  const int wr = wid >> 1, wc = wid & 1;
  const int tM = blockIdx.y * 128, tN = blockIdx.x * 128;

  f32x4 acc[4][4] = {};

  for (int k0 = 0; k0 < K; k0 += 32) {
    int4 av[2], bv[2];
#pragma unroll
    for (int h = 0; h < 2; ++h) {
      int c = h * 256 + tid;               // 512 x 16B chunks per buffer
      int row = c >> 2;
      int srchi = (c & 3) ^ ((row >> 1) & 3);
      av[h] = *(const int4*)(A + (size_t)(tM + row) * K + k0 + srchi * 8);
      bv[h] = *(const int4*)(Bt + (size_t)(tN + row) * K + k0 + srchi * 8);
    }
    __syncthreads();  // previous tile's reads done
#pragma unroll
    for (int h = 0; h < 2; ++h) {
      int c = h * 256 + tid;
      *(int4*)(As + c * 8) = av[h];
      *(int4*)(Bs + c * 8) = bv[h];
    }
    __syncthreads();

    short8 af[4], bfr[4];
#pragma unroll
    for (int m = 0; m < 4; ++m) {
      int row = wr * 64 + m * 16 + lo;
      int slot = hi ^ ((row >> 1) & 3);
      af[m] = *(const short8*)(As + row * 32 + slot * 8);
    }
#pragma unroll
    for (int n = 0; n < 4; ++n) {
      int row = wc * 64 + n * 16 + lo;
      int slot = hi ^ ((row >> 1) & 3);
      bfr[n] = *(const short8*)(Bs + row * 32 + slot * 8);
    }
#pragma unroll
    for (int m = 0; m < 4; ++m)
#pragma unroll
      for (int n = 0; n < 4; ++n)
        acc[m][n] = MFMA_BF16(af[m], bfr[n], acc[m][n]);
  }

#pragma unroll
  for (int n = 0; n < 4; ++n) {
    int col = tN + wc * 64 + n * 16 + lo;
    float bs = bias[col];
    if (EPI == 0) {
      int which = col >> 10;
      int hh = (col >> 6) & 15, d = col & 63;
#pragma unroll
      for (int m = 0; m < 4; ++m) {
        int rbase = tM + wr * 64 + m * 16 + hi * 4;  // global row (4 consecutive)
        int b = rbase >> 11, nn = rbase & 2047;
        int bh = b * kH + hh;
        if (which == 2) {
          ushort4 pk;
          pk.x = (unsigned short)f2bfbits(acc[m][n][0] + bs);
          pk.y = (unsigned short)f2bfbits(acc[m][n][1] + bs);
          pk.z = (unsigned short)f2bfbits(acc[m][n][2] + bs);
          pk.w = (unsigned short)f2bfbits(acc[m][n][3] + bs);
          *(ushort4*)(vT + ((size_t)bh * kHd + d) * kN + nn) = pk;
        } else {
          bf16* dst = (which == 0) ? q : kk;
#pragma unroll
          for (int r = 0; r < 4; ++r)
            dst[((size_t)bh * kN + nn + r) * kHd + d] = __float2bfloat16(acc[m][n][r] + bs);
        }
      }
    } else {
#pragma unroll
      for (int m = 0; m < 4; ++m) {
        int rbase = tM + wr * 64 + m * 16 + hi * 4;
#pragma unroll
        for (int r = 0; r < 4; ++r)
          out[(size_t)(rbase + r) * Nout + col] = acc[m][n][r] + bs;
      }
    }
  }
}

// ---------- flash attention: softmax(scale * q k^T) @ v ----------
// grid (N/128, H, B); 4 waves x 32 q-rows; KV tiles of 64; vT gives contiguous PV B-frags.
__global__ __launch_bounds__(256) void k_attn(
    const bf16* __restrict__ q, const bf16* __restrict__ k, const bf16* __restrict__ vT,
    const float* __restrict__ scale, bf16* __restrict__ wout) {
  __shared__ short8 PlV[4][320];  // per-wave P buffer [32][80] bf16 (pad 64->80: 16B rows, conflict-lite)
  const int tid = threadIdx.x, wid = tid >> 6, lane = tid & 63;
  const int hi = lane >> 4, lo = lane & 15;
  short* Pl = (short*)&PlV[wid][0];

  const int h = blockIdx.y, b = blockIdx.z;
  const int bh = b * kH + h;
  const bf16* qp = q + (size_t)bh * kN * kHd;
  const bf16* kp = k + (size_t)bh * kN * kHd;
  const bf16* vp = vT + (size_t)bh * kHd * kN;
  const float sc = scale[bh];
  const int qb = blockIdx.x * 128 + wid * 32;

  short8 aq[2][2];  // Q frags hoisted: [m-frag][k-step]
#pragma unroll
  for (int m = 0; m < 2; ++m)
#pragma unroll
    for (int ks = 0; ks < 2; ++ks)
      aq[m][ks] = *(const short8*)(qp + (size_t)(qb + m * 16 + lo) * kHd + ks * 32 + hi * 8);

  f32x4 oacc[2][4] = {};
  float runm[2][4], lsum[2][4];
#pragma unroll
  for (int m = 0; m < 2; ++m)
#pragma unroll
    for (int r = 0; r < 4; ++r) { runm[m][r] = -1e30f; lsum[m][r] = 0.f; }

  for (int t = 0; t < kN / 64; ++t) {
    __syncthreads();  // keep waves in phase for K/V L1 reuse (no cross-wave LDS sharing)
    const int kv0 = t * 64;
    f32x4 sacc[2][4] = {};
#pragma unroll
    for (int ks = 0; ks < 2; ++ks) {
      short8 kf[4];
#pragma unroll
      for (int j = 0; j < 4; ++j)
        kf[j] = *(const short8*)(kp + (size_t)(kv0 + j * 16 + lo) * kHd + ks * 32 + hi * 8);
#pragma unroll
      for (int m = 0; m < 2; ++m)
#pragma unroll
        for (int j = 0; j < 4; ++j)
          sacc[m][j] = MFMA_BF16(aq[m][ks], kf[j], sacc[m][j]);
    }

    // online softmax in C/D layout: row = m*16 + hi*4 + r, cols j*16 + lo
#pragma unroll
    for (int m = 0; m < 2; ++m)
#pragma unroll
      for (int r = 0; r < 4; ++r) {
        float mx = sacc[m][0][r];
#pragma unroll
        for (int j = 1; j < 4; ++j) mx = fmaxf(mx, sacc[m][j][r]);
        mx *= sc;  // sc > 0, so max commutes with scaling
#pragma unroll
        for (int off = 1; off < 16; off <<= 1) mx = fmaxf(mx, __shfl_xor(mx, off));
        const float nm = fmaxf(runm[m][r], mx);
        const float corr = __expf(runm[m][r] - nm);
        runm[m][r] = nm;
        float p[4], rs = 0.f;
#pragma unroll
        for (int j = 0; j < 4; ++j) {
          p[j] = __expf(sacc[m][j][r] * sc - nm);
          rs += p[j];
        }
#pragma unroll
        for (int off = 1; off < 16; off <<= 1) rs += __shfl_xor(rs, off);
        lsum[m][r] = lsum[m][r] * corr + rs;
#pragma unroll
        for (int jd = 0; jd < 4; ++jd) oacc[m][jd][r] *= corr;
#pragma unroll
        for (int j = 0; j < 4; ++j)
          Pl[(m * 16 + hi * 4 + r) * 80 + j * 16 + lo] = f2bfbits(p[j]);
      }

    // PV: A-frag from P-LDS (re-layout), B-frag contiguous from vT
#pragma unroll
    for (int ks = 0; ks < 2; ++ks) {
      short8 pf[2], vf[4];
#pragma unroll
      for (int m = 0; m < 2; ++m)
        pf[m] = *(const short8*)(Pl + (m * 16 + lo) * 80 + ks * 32 + hi * 8);
#pragma unroll
      for (int jd = 0; jd < 4; ++jd)
        vf[jd] = *(const short8*)(vp + (size_t)(jd * 16 + lo) * kN + kv0 + ks * 32 + hi * 8);
#pragma unroll
      for (int m = 0; m < 2; ++m)
#pragma unroll
        for (int jd = 0; jd < 4; ++jd)
          oacc[m][jd] = MFMA_BF16(pf[m], vf[jd], oacc[m][jd]);
    }
  }

#pragma unroll
  for (int m = 0; m < 2; ++m)
#pragma unroll
    for (int jd = 0; jd < 4; ++jd)
#pragma unroll
      for (int r = 0; r < 4; ++r) {
        int n = qb + m * 16 + hi * 4 + r;
        float val = oacc[m][jd][r] / lsum[m][r];
        wout[((size_t)b * kN + n) * kD + h * kHd + jd * 16 + lo] = __float2bfloat16(val);
      }
}

extern "C" void kernel_launch(void* const* d_in, const int* in_sizes, int n_in,
                              void* d_out, int out_size, void* d_ws, size_t ws_size,
                              hipStream_t stream) {
  const float* x     = (const float*)d_in[0];
  const float* Wqkv  = (const float*)d_in[1];
  const float* bqkv  = (const float*)d_in[2];
  const float* Wproj = (const float*)d_in[3];
  const float* bproj = (const float*)d_in[4];
  float* out = (float*)d_out;

  char* ws = (char*)d_ws;
  size_t off = 0;
  auto alloc = [&](size_t bytes) {
    char* p = ws + off;
    off = (off + bytes + 255) & ~(size_t)255;
    return p;
  };
  bf16* xb   = (bf16*)alloc((size_t)kB * kN * kD * 2);        // 16 MB
  bf16* WqT  = (bf16*)alloc((size_t)3 * kD * kD * 2);         // 6 MB  [3D][D]
  bf16* WpT  = (bf16*)alloc((size_t)kD * kD * 2);             // 2 MB  [D][D]
  bf16* qd   = (bf16*)alloc((size_t)kB * kH * kN * kHd * 2);  // 8 MB  [BH][N][hd]
  bf16* kd   = (bf16*)alloc((size_t)kB * kH * kN * kHd * 2);  // 8 MB
  bf16* vTd  = (bf16*)alloc((size_t)kB * kH * kHd * kN * 2);  // 8 MB  [BH][hd][N]
  bf16* wo   = (bf16*)alloc((size_t)kB * kN * kD * 2);        // 8 MB  [B][N][D]
  float* colsum = (float*)alloc((size_t)kB * kD * 4);
  float* froqsq = (float*)alloc((size_t)kB * kH * 4);
  float* scl    = (float*)alloc((size_t)kB * kH * 4);

  hipMemsetAsync(colsum, 0, (size_t)kB * kD * 4, stream);

  k_convert<<<dim3(kB * kN * kD / 4 / 256), 256, 0, stream>>>(x, xb, kB * kN * kD / 4);
  k_transpose<<<dim3(3 * kD / 32, kD / 32), 256, 0, stream>>>(Wqkv, WqT, kD, 3 * kD);
  k_transpose<<<dim3(kD / 32, kD / 32), 256, 0, stream>>>(Wproj, WpT, kD, kD);
  k_colsum<<<dim3(kD / 256, kN / 256, kB), 256, 0, stream>>>(x, colsum);

  k_gemm<0><<<dim3(3 * kD / 128, kB * kN / 128), 256, 0, stream>>>(
      xb, WqT, bqkv, kD, 3 * kD, qd, kd, vTd, nullptr);

  k_froq<<<kB * kH, 256, 0, stream>>>(qd, froqsq);
  k_scale<<<1, 32, 0, stream>>>(colsum, froqsq, scl);

  k_attn<<<dim3(kN / 128, kH, kB), 256, 0, stream>>>(qd, kd, vTd, scl, wo);

  k_gemm<1><<<dim3(kD / 128, kB * kN / 128), 256, 0, stream>>>(
      wo, WpT, bproj, kD, kD, nullptr, nullptr, nullptr, out);
}

// Round 4
// 406.573 us; speedup vs baseline: 1.3033x; 1.3033x over previous
//
#include <hip/hip_runtime.h>
#include <hip/hip_bf16.h>
#include <stdint.h>

using bf16   = __hip_bfloat16;
using short8 = __attribute__((ext_vector_type(8))) short;
using f32x4  = __attribute__((ext_vector_type(4))) float;

#define MFMA_BF16(a, b, c) __builtin_amdgcn_mfma_f32_16x16x32_bf16((a), (b), (c), 0, 0, 0)

static constexpr int   kB = 2, kN = 2048, kD = 1024, kH = 16, kHd = 64;
static constexpr float kAlpha = 1.0f;
static constexpr float kLog2e = 1.44269504088896f;

__device__ __forceinline__ short f2bfbits(float x) {
  bf16 h = __float2bfloat16(x);
  return __builtin_bit_cast(short, h);
}
__device__ __forceinline__ float bfbits2f(short s) {
  unsigned u = ((unsigned)(unsigned short)s) << 16;
  return __builtin_bit_cast(float, u);
}

// async global->LDS, 16B per lane. LDS dest must be wave-uniform base + lane*16
// (we pass per-lane ptrs that satisfy exactly that). Global source is per-lane.
__device__ __forceinline__ void gload_lds16(const void* g, void* l) {
  __builtin_amdgcn_global_load_lds(
      (const __attribute__((address_space(1))) void*)g,
      (__attribute__((address_space(3))) void*)l, 16, 0, 0);
}

// ---------- fp32 -> bf16 contiguous convert ----------
__global__ void k_convert(const float* __restrict__ in, bf16* __restrict__ out, int n4) {
  int i = blockIdx.x * 256 + threadIdx.x;
  if (i >= n4) return;
  float4 v = *(const float4*)(in + (size_t)i * 4);
  ushort4 u;
  u.x = (unsigned short)f2bfbits(v.x);
  u.y = (unsigned short)f2bfbits(v.y);
  u.z = (unsigned short)f2bfbits(v.z);
  u.w = (unsigned short)f2bfbits(v.w);
  *(ushort4*)(out + (size_t)i * 4) = u;
}

// ---------- W[K][N] fp32 -> Wt[N][K] bf16 (LDS tile transpose) ----------
__global__ void k_transpose(const float* __restrict__ W, bf16* __restrict__ Wt, int K, int N) {
  __shared__ float tile[32][33];
  int bk = blockIdx.y * 32, bn = blockIdx.x * 32;
  int tx = threadIdx.x & 31, ty = threadIdx.x >> 5;  // ty 0..7
#pragma unroll
  for (int i = 0; i < 4; ++i)
    tile[ty + i * 8][tx] = W[(size_t)(bk + ty + i * 8) * N + bn + tx];
  __syncthreads();
#pragma unroll
  for (int i = 0; i < 4; ++i)
    Wt[(size_t)(bn + ty + i * 8) * K + bk + tx] = __float2bfloat16(tile[tx][ty + i * 8]);
}

// ---------- per-(b,d) sum |x| over tokens (atomic partials) ----------
__global__ void k_colsum(const float* __restrict__ x, float* __restrict__ colsum) {
  int b = blockIdx.z;
  int d = blockIdx.x * 256 + threadIdx.x;
  int n0 = blockIdx.y * 256;
  const float* px = x + ((size_t)b * kN + n0) * kD + d;
  float s = 0.f;
  for (int n = 0; n < 256; ++n) s += fabsf(px[(size_t)n * kD]);
  atomicAdd(&colsum[b * kD + d], s);
}

// ---------- sum q^2 per (b,h), 8 slices per bh (atomic) ----------
__global__ void k_froq(const bf16* __restrict__ q, float* __restrict__ froqsq) {
  int bh = blockIdx.x;
  const short* p = (const short*)(q + (size_t)bh * kN * kHd) + blockIdx.y * (kN * kHd / 8);
  float s = 0.f;
  for (int i = threadIdx.x; i < kN * kHd / 8 / 8; i += 256) {
    short8 v = *(const short8*)(p + (size_t)i * 8);
#pragma unroll
    for (int j = 0; j < 8; ++j) { float f = bfbits2f(v[j]); s += f * f; }
  }
#pragma unroll
  for (int off = 32; off >= 1; off >>= 1) s += __shfl_down(s, off);
  __shared__ float red[4];
  if ((threadIdx.x & 63) == 0) red[threadIdx.x >> 6] = s;
  __syncthreads();
  if (threadIdx.x == 0) atomicAdd(&froqsq[bh], red[0] + red[1] + red[2] + red[3]);
}

// ---------- scale[b,h] = 2*alpha / (sqrt(froq_sq) * max_d colsum) ----------
__global__ void k_scale(const float* __restrict__ colsum, const float* __restrict__ froqsq,
                        float* __restrict__ scale) {
  int b = threadIdx.x >> 7, t = threadIdx.x & 127;  // 128 threads per batch
  float m0 = 0.f;
  for (int d = t; d < kD; d += 128) m0 = fmaxf(m0, colsum[b * kD + d]);
#pragma unroll
  for (int off = 32; off >= 1; off >>= 1) m0 = fmaxf(m0, __shfl_xor(m0, off));
  __shared__ float part[4];
  if ((threadIdx.x & 63) == 0) part[threadIdx.x >> 6] = m0;
  __syncthreads();
  if (threadIdx.x < kB * kH) {
    int bb = threadIdx.x >> 4;
    float mx = fmaxf(part[bb * 2], part[bb * 2 + 1]);
    scale[threadIdx.x] = 2.0f * kAlpha / (sqrtf(froqsq[threadIdx.x]) * mx);
  }
}

// ---------- bf16 GEMM: C[M][Nout] = A[M][K] @ Bt[Nout][K]^T + bias ----------
// 128x128 tile, BK=32, 4 waves (2x2). global_load_lds (16B) staging with the slot-XOR
// swizzle applied on the GLOBAL source (linear LDS dest) per rule #21.
// Bijective XCD swizzle on a flat grid of GX*32 blocks (GX*32 % 8 == 0).
template <int EPI, int GX>
__global__ __launch_bounds__(256) void k_gemm(
    const bf16* __restrict__ A, const bf16* __restrict__ Bt,
    const float* __restrict__ bias, int K, int Nout,
    bf16* __restrict__ q, bf16* __restrict__ kk, bf16* __restrict__ vT,
    float* __restrict__ out) {
  __shared__ short8 AsV[512], BsV[512];
  short* As = (short*)AsV;
  short* Bs = (short*)BsV;
  const int tid = threadIdx.x;
  const int lane = tid & 63, wid = tid >> 6;
  const int hi = lane >> 4, lo = lane & 15;
  const int wr = wid >> 1, wc = wid & 1;
  const int bid = blockIdx.x;
  const int nid = (bid & 7) * (GX * 4) + (bid >> 3);  // XCD-contiguous chunks
  const int tN = (nid % GX) * 128, tM = (nid / GX) * 128;

  f32x4 acc[4][4] = {};

  for (int k0 = 0; k0 < K; k0 += 32) {
    __syncthreads();  // previous tile's reads done
#pragma unroll
    for (int h = 0; h < 2; ++h) {
      int c = h * 256 + tid;               // 512 x 16B chunks per buffer
      int row = c >> 2;
      int srchi = (c & 3) ^ ((row >> 1) & 3);   // pre-swizzled global source
      gload_lds16(A + (size_t)(tM + row) * K + k0 + srchi * 8, As + c * 8);
      gload_lds16(Bt + (size_t)(tN + row) * K + k0 + srchi * 8, Bs + c * 8);
    }
    __syncthreads();  // drains vmcnt -> loads landed

    short8 af[4], bfr[4];
#pragma unroll
    for (int m = 0; m < 4; ++m) {
      int row = wr * 64 + m * 16 + lo;
      int slot = hi ^ ((row >> 1) & 3);
      af[m] = *(const short8*)(As + row * 32 + slot * 8);
    }
#pragma unroll
    for (int n = 0; n < 4; ++n) {
      int row = wc * 64 + n * 16 + lo;
      int slot = hi ^ ((row >> 1) & 3);
      bfr[n] = *(const short8*)(Bs + row * 32 + slot * 8);
    }
    __builtin_amdgcn_s_setprio(1);
#pragma unroll
    for (int m = 0; m < 4; ++m)
#pragma unroll
      for (int n = 0; n < 4; ++n)
        acc[m][n] = MFMA_BF16(af[m], bfr[n], acc[m][n]);
    __builtin_amdgcn_s_setprio(0);
  }

#pragma unroll
  for (int n = 0; n < 4; ++n) {
    int col = tN + wc * 64 + n * 16 + lo;
    float bs = bias[col];
    if (EPI == 0) {
      int which = col >> 10;
      int hh = (col >> 6) & 15, d = col & 63;
#pragma unroll
      for (int m = 0; m < 4; ++m) {
        int rbase = tM + wr * 64 + m * 16 + hi * 4;  // global row (4 consecutive)
        int b = rbase >> 11, nn = rbase & 2047;
        int bh = b * kH + hh;
        if (which == 2) {
          ushort4 pk;
          pk.x = (unsigned short)f2bfbits(acc[m][n][0] + bs);
          pk.y = (unsigned short)f2bfbits(acc[m][n][1] + bs);
          pk.z = (unsigned short)f2bfbits(acc[m][n][2] + bs);
          pk.w = (unsigned short)f2bfbits(acc[m][n][3] + bs);
          *(ushort4*)(vT + ((size_t)bh * kHd + d) * kN + nn) = pk;
        } else {
          bf16* dst = (which == 0) ? q : kk;
#pragma unroll
          for (int r = 0; r < 4; ++r)
            dst[((size_t)bh * kN + nn + r) * kHd + d] = __float2bfloat16(acc[m][n][r] + bs);
        }
      }
    } else {
#pragma unroll
      for (int m = 0; m < 4; ++m) {
        int rbase = tM + wr * 64 + m * 16 + hi * 4;
#pragma unroll
        for (int r = 0; r < 4; ++r)
          out[(size_t)(rbase + r) * Nout + col] = acc[m][n][r] + bs;
      }
    }
  }
}

// ---------- flash attention: softmax(scale * q k^T) @ v ----------
// Flat grid 1024 (XCD-swizzled so the 32 blocks of one (b,h) share an XCD L2).
// 4 independent waves x 16 q-rows, NO barriers. KV tiles of 64. V loads issued
// before softmax (latency hidden). Defer-max (T13, thr=8 in base-2 domain).
__global__ __launch_bounds__(256, 4) void k_attn(
    const bf16* __restrict__ q, const bf16* __restrict__ k, const bf16* __restrict__ vT,
    const float* __restrict__ scale, bf16* __restrict__ wout) {
  __shared__ short Pl_all[4][16 * 72];  // per-wave P [16 rows][72 shorts] (144B rows)
  const int tid = threadIdx.x, wid = tid >> 6, lane = tid & 63;
  const int hi = lane >> 4, lo = lane & 15;
  short* Pl = &Pl_all[wid][0];

  const int bid = blockIdx.x;
  const int nid = (bid & 7) * 128 + (bid >> 3);
  const int qt = nid & 31;   // q-tile (64 rows)
  const int bh = nid >> 5;   // 0..31
  const int b = bh >> 4, h = bh & 15;
  const bf16* qp = q + (size_t)bh * kN * kHd;
  const bf16* kp = k + (size_t)bh * kN * kHd;
  const bf16* vp = vT + (size_t)bh * kHd * kN;
  const float sc2 = scale[bh] * kLog2e;  // base-2 softmax domain
  const int qb = qt * 64 + wid * 16;

  short8 aq[2];
#pragma unroll
  for (int ks = 0; ks < 2; ++ks)
    aq[ks] = *(const short8*)(qp + (size_t)(qb + lo) * kHd + ks * 32 + hi * 8);

  f32x4 oacc[4] = {};
  float runm[4], lsum[4];
#pragma unroll
  for (int r = 0; r < 4; ++r) { runm[r] = -1e30f; lsum[r] = 0.f; }

  for (int t = 0; t < kN / 64; ++t) {
    const int kv0 = t * 64;
    f32x4 sacc[4] = {};
#pragma unroll
    for (int ks = 0; ks < 2; ++ks) {
      short8 kf[4];
#pragma unroll
      for (int j = 0; j < 4; ++j)
        kf[j] = *(const short8*)(kp + (size_t)(kv0 + j * 16 + lo) * kHd + ks * 32 + hi * 8);
      __builtin_amdgcn_s_setprio(1);
#pragma unroll
      for (int j = 0; j < 4; ++j)
        sacc[j] = MFMA_BF16(aq[ks], kf[j], sacc[j]);
      __builtin_amdgcn_s_setprio(0);
    }
    // issue V loads now -- independent of softmax, hides HBM/L2 latency under it
    short8 vf[2][4];
#pragma unroll
    for (int ks = 0; ks < 2; ++ks)
#pragma unroll
      for (int jd = 0; jd < 4; ++jd)
        vf[ks][jd] = *(const short8*)(vp + (size_t)(jd * 16 + lo) * kN + kv0 + ks * 32 + hi * 8);

    // online softmax; C/D layout: row = hi*4+r (q), col = j*16+lo (kv)
#pragma unroll
    for (int r = 0; r < 4; ++r) {
      float mx = fmaxf(fmaxf(sacc[0][r], sacc[1][r]), fmaxf(sacc[2][r], sacc[3][r]));
      mx *= sc2;
#pragma unroll
      for (int off = 1; off < 16; off <<= 1) mx = fmaxf(mx, __shfl_xor(mx, off));
      if (!__all(mx - runm[r] <= 8.0f)) {  // defer-max: rescale only on real growth
        float nm = fmaxf(runm[r], mx);
        float corr = exp2f(runm[r] - nm);
        lsum[r] *= corr;
#pragma unroll
        for (int jd = 0; jd < 4; ++jd) oacc[jd][r] *= corr;
        runm[r] = nm;
      }
      float rs = 0.f;
#pragma unroll
      for (int j = 0; j < 4; ++j) {
        float p = exp2f(sacc[j][r] * sc2 - runm[r]);
        rs += p;
        Pl[(hi * 4 + r) * 72 + j * 16 + lo] = f2bfbits(p);
      }
#pragma unroll
      for (int off = 1; off < 16; off <<= 1) rs += __shfl_xor(rs, off);
      lsum[r] += rs;
    }

    // PV: A-frag from P-LDS (row=lo), B-frag contiguous from vT
#pragma unroll
    for (int ks = 0; ks < 2; ++ks) {
      short8 pf = *(const short8*)(Pl + lo * 72 + ks * 32 + hi * 8);
      __builtin_amdgcn_s_setprio(1);
#pragma unroll
      for (int jd = 0; jd < 4; ++jd)
        oacc[jd] = MFMA_BF16(pf, vf[ks][jd], oacc[jd]);
      __builtin_amdgcn_s_setprio(0);
    }
  }

#pragma unroll
  for (int jd = 0; jd < 4; ++jd)
#pragma unroll
    for (int r = 0; r < 4; ++r) {
      int n = qb + hi * 4 + r;
      float val = oacc[jd][r] / lsum[r];
      wout[((size_t)b * kN + n) * kD + h * kHd + jd * 16 + lo] = __float2bfloat16(val);
    }
}

extern "C" void kernel_launch(void* const* d_in, const int* in_sizes, int n_in,
                              void* d_out, int out_size, void* d_ws, size_t ws_size,
                              hipStream_t stream) {
  const float* x     = (const float*)d_in[0];
  const float* Wqkv  = (const float*)d_in[1];
  const float* bqkv  = (const float*)d_in[2];
  const float* Wproj = (const float*)d_in[3];
  const float* bproj = (const float*)d_in[4];
  float* out = (float*)d_out;

  char* ws = (char*)d_ws;
  size_t off = 0;
  auto alloc = [&](size_t bytes) {
    char* p = ws + off;
    off = (off + bytes + 255) & ~(size_t)255;
    return p;
  };
  bf16* xb   = (bf16*)alloc((size_t)kB * kN * kD * 2);        // 16 MB
  bf16* WqT  = (bf16*)alloc((size_t)3 * kD * kD * 2);         // 6 MB  [3D][D]
  bf16* WpT  = (bf16*)alloc((size_t)kD * kD * 2);             // 2 MB  [D][D]
  bf16* qd   = (bf16*)alloc((size_t)kB * kH * kN * kHd * 2);  // 8 MB  [BH][N][hd]
  bf16* kd   = (bf16*)alloc((size_t)kB * kH * kN * kHd * 2);  // 8 MB
  bf16* vTd  = (bf16*)alloc((size_t)kB * kH * kHd * kN * 2);  // 8 MB  [BH][hd][N]
  bf16* wo   = (bf16*)alloc((size_t)kB * kN * kD * 2);        // 8 MB  [B][N][D]
  float* colsum = (float*)alloc((size_t)kB * kD * 4);         // 8192 B
  float* froqsq = (float*)alloc((size_t)kB * kH * 4);         // at colsum+8192
  float* scl    = (float*)alloc((size_t)kB * kH * 4);

  // zero colsum (8192 B) + froqsq slot (256 B reserved) in one memset
  hipMemsetAsync(colsum, 0, (size_t)kB * kD * 4 + 256, stream);

  k_convert<<<dim3(kB * kN * kD / 4 / 256), 256, 0, stream>>>(x, xb, kB * kN * kD / 4);
  k_transpose<<<dim3(3 * kD / 32, kD / 32), 256, 0, stream>>>(Wqkv, WqT, kD, 3 * kD);
  k_transpose<<<dim3(kD / 32, kD / 32), 256, 0, stream>>>(Wproj, WpT, kD, kD);
  k_colsum<<<dim3(kD / 256, kN / 256, kB), 256, 0, stream>>>(x, colsum);

  k_gemm<0, 24><<<dim3(24 * 32), 256, 0, stream>>>(
      xb, WqT, bqkv, kD, 3 * kD, qd, kd, vTd, nullptr);

  k_froq<<<dim3(kB * kH, 8), 256, 0, stream>>>(qd, froqsq);
  k_scale<<<1, 256, 0, stream>>>(colsum, froqsq, scl);

  k_attn<<<dim3(1024), 256, 0, stream>>>(qd, kd, vTd, scl, wo);

  k_gemm<1, 8><<<dim3(8 * 32), 256, 0, stream>>>(
      wo, WpT, bproj, kD, kD, nullptr, nullptr, nullptr, out);
}

// Round 12
// 305.878 us; speedup vs baseline: 1.7323x; 1.3292x over previous
//
#include <hip/hip_runtime.h>
#include <hip/hip_bf16.h>
#include <stdint.h>

using bf16   = __hip_bfloat16;
using short8 = __attribute__((ext_vector_type(8))) short;
using f32x4  = __attribute__((ext_vector_type(4))) float;

#define MFMA_BF16(a, b, c) __builtin_amdgcn_mfma_f32_16x16x32_bf16((a), (b), (c), 0, 0, 0)

static constexpr int   kB = 2, kN = 2048, kD = 1024, kH = 16, kHd = 64;
static constexpr float kAlpha = 1.0f;
static constexpr float kLog2e = 1.44269504088896f;

__device__ __forceinline__ short f2bfbits(float x) {
  bf16 h = __float2bfloat16(x);
  return __builtin_bit_cast(short, h);
}
__device__ __forceinline__ float bfbits2f(short s) {
  unsigned u = ((unsigned)(unsigned short)s) << 16;
  return __builtin_bit_cast(float, u);
}

// async global->LDS, 16B per lane. LDS dest must be wave-uniform base + lane*16.
__device__ __forceinline__ void gload_lds16(const void* g, void* l) {
  __builtin_amdgcn_global_load_lds(
      (const __attribute__((address_space(1))) void*)g,
      (__attribute__((address_space(3))) void*)l, 16, 0, 0);
}

// ---------- fp32 -> bf16 contiguous convert ----------
__global__ void k_convert(const float* __restrict__ in, bf16* __restrict__ out, int n4) {
  int i = blockIdx.x * 256 + threadIdx.x;
  if (i >= n4) return;
  float4 v = *(const float4*)(in + (size_t)i * 4);
  ushort4 u;
  u.x = (unsigned short)f2bfbits(v.x);
  u.y = (unsigned short)f2bfbits(v.y);
  u.z = (unsigned short)f2bfbits(v.z);
  u.w = (unsigned short)f2bfbits(v.w);
  *(ushort4*)(out + (size_t)i * 4) = u;
}

// ---------- W[K][N] fp32 -> Wt[N][K] bf16 (LDS tile transpose) ----------
__global__ void k_transpose(const float* __restrict__ W, bf16* __restrict__ Wt, int K, int N) {
  __shared__ float tile[32][33];
  int bk = blockIdx.y * 32, bn = blockIdx.x * 32;
  int tx = threadIdx.x & 31, ty = threadIdx.x >> 5;  // ty 0..7
#pragma unroll
  for (int i = 0; i < 4; ++i)
    tile[ty + i * 8][tx] = W[(size_t)(bk + ty + i * 8) * N + bn + tx];
  __syncthreads();
#pragma unroll
  for (int i = 0; i < 4; ++i)
    Wt[(size_t)(bn + ty + i * 8) * K + bk + tx] = __float2bfloat16(tile[tx][ty + i * 8]);
}

// ---------- per-(b,d) sum |x| over tokens (atomic partials) ----------
__global__ void k_colsum(const float* __restrict__ x, float* __restrict__ colsum) {
  int b = blockIdx.z;
  int d = blockIdx.x * 256 + threadIdx.x;
  int n0 = blockIdx.y * 256;
  const float* px = x + ((size_t)b * kN + n0) * kD + d;
  float s = 0.f;
  for (int n = 0; n < 256; ++n) s += fabsf(px[(size_t)n * kD]);
  atomicAdd(&colsum[b * kD + d], s);
}

// ---------- sum q^2 per (b,h), 8 slices per bh (atomic) ----------
__global__ void k_froq(const bf16* __restrict__ q, float* __restrict__ froqsq) {
  int bh = blockIdx.x;
  const short* p = (const short*)(q + (size_t)bh * kN * kHd) + blockIdx.y * (kN * kHd / 8);
  float s = 0.f;
  for (int i = threadIdx.x; i < kN * kHd / 8 / 8; i += 256) {
    short8 v = *(const short8*)(p + (size_t)i * 8);
#pragma unroll
    for (int j = 0; j < 8; ++j) { float f = bfbits2f(v[j]); s += f * f; }
  }
#pragma unroll
  for (int off = 32; off >= 1; off >>= 1) s += __shfl_down(s, off);
  __shared__ float red[4];
  if ((threadIdx.x & 63) == 0) red[threadIdx.x >> 6] = s;
  __syncthreads();
  if (threadIdx.x == 0) atomicAdd(&froqsq[bh], red[0] + red[1] + red[2] + red[3]);
}

// ---------- scale[b,h] = 2*alpha / (sqrt(froq_sq) * max_d colsum) ----------
__global__ void k_scale(const float* __restrict__ colsum, const float* __restrict__ froqsq,
                        float* __restrict__ scale) {
  int b = threadIdx.x >> 7, t = threadIdx.x & 127;  // 128 threads per batch
  float m0 = 0.f;
  for (int d = t; d < kD; d += 128) m0 = fmaxf(m0, colsum[b * kD + d]);
#pragma unroll
  for (int off = 32; off >= 1; off >>= 1) m0 = fmaxf(m0, __shfl_xor(m0, off));
  __shared__ float part[4];
  if ((threadIdx.x & 63) == 0) part[threadIdx.x >> 6] = m0;
  __syncthreads();
  if (threadIdx.x < kB * kH) {
    int bb = threadIdx.x >> 4;
    float mx = fmaxf(part[bb * 2], part[bb * 2 + 1]);
    scale[threadIdx.x] = 2.0f * kAlpha / (sqrtf(froqsq[threadIdx.x]) * mx);
  }
}

// ---------- bf16 GEMM: C[M][Nout] = A[M][K] @ Bt[Nout][K]^T + bias ----------
// 128x128 tile, BK=32, 4 waves (2x2). global_load_lds (16B) staging; slot-XOR
// swizzle on the GLOBAL source (linear LDS dest). Bijective XCD swizzle.
template <int EPI, int GX>
__global__ __launch_bounds__(256) void k_gemm(
    const bf16* __restrict__ A, const bf16* __restrict__ Bt,
    const float* __restrict__ bias, int K, int Nout,
    bf16* __restrict__ q, bf16* __restrict__ kk, bf16* __restrict__ vT,
    float* __restrict__ out) {
  __shared__ short8 AsV[512], BsV[512];
  short* As = (short*)AsV;
  short* Bs = (short*)BsV;
  const int tid = threadIdx.x;
  const int lane = tid & 63, wid = tid >> 6;
  const int hi = lane >> 4, lo = lane & 15;
  const int wr = wid >> 1, wc = wid & 1;
  const int bid = blockIdx.x;
  const int nid = (bid & 7) * (GX * 4) + (bid >> 3);  // XCD-contiguous chunks
  const int tN = (nid % GX) * 128, tM = (nid / GX) * 128;

  f32x4 acc[4][4] = {};

  for (int k0 = 0; k0 < K; k0 += 32) {
    __syncthreads();  // previous tile's reads done
#pragma unroll
    for (int h = 0; h < 2; ++h) {
      int c = h * 256 + tid;               // 512 x 16B chunks per buffer
      int row = c >> 2;
      int srchi = (c & 3) ^ ((row >> 1) & 3);   // pre-swizzled global source
      gload_lds16(A + (size_t)(tM + row) * K + k0 + srchi * 8, As + c * 8);
      gload_lds16(Bt + (size_t)(tN + row) * K + k0 + srchi * 8, Bs + c * 8);
    }
    __syncthreads();  // drains vmcnt -> loads landed

    short8 af[4], bfr[4];
#pragma unroll
    for (int m = 0; m < 4; ++m) {
      int row = wr * 64 + m * 16 + lo;
      int slot = hi ^ ((row >> 1) & 3);
      af[m] = *(const short8*)(As + row * 32 + slot * 8);
    }
#pragma unroll
    for (int n = 0; n < 4; ++n) {
      int row = wc * 64 + n * 16 + lo;
      int slot = hi ^ ((row >> 1) & 3);
      bfr[n] = *(const short8*)(Bs + row * 32 + slot * 8);
    }
    __builtin_amdgcn_s_setprio(1);
#pragma unroll
    for (int m = 0; m < 4; ++m)
#pragma unroll
      for (int n = 0; n < 4; ++n)
        acc[m][n] = MFMA_BF16(af[m], bfr[n], acc[m][n]);
    __builtin_amdgcn_s_setprio(0);
  }

#pragma unroll
  for (int n = 0; n < 4; ++n) {
    int col = tN + wc * 64 + n * 16 + lo;
    float bs = bias[col];
    if (EPI == 0) {
      int which = col >> 10;
      int hh = (col >> 6) & 15, d = col & 63;
#pragma unroll
      for (int m = 0; m < 4; ++m) {
        int rbase = tM + wr * 64 + m * 16 + hi * 4;  // global row (4 consecutive)
        int b = rbase >> 11, nn = rbase & 2047;
        int bh = b * kH + hh;
        if (which == 2) {
          ushort4 pk;
          pk.x = (unsigned short)f2bfbits(acc[m][n][0] + bs);
          pk.y = (unsigned short)f2bfbits(acc[m][n][1] + bs);
          pk.z = (unsigned short)f2bfbits(acc[m][n][2] + bs);
          pk.w = (unsigned short)f2bfbits(acc[m][n][3] + bs);
          *(ushort4*)(vT + ((size_t)bh * kHd + d) * kN + nn) = pk;
        } else {
          bf16* dst = (which == 0) ? q : kk;
#pragma unroll
          for (int r = 0; r < 4; ++r)
            dst[((size_t)bh * kN + nn + r) * kHd + d] = __float2bfloat16(acc[m][n][r] + bs);
        }
      }
    } else {
#pragma unroll
      for (int m = 0; m < 4; ++m) {
        int rbase = tM + wr * 64 + m * 16 + hi * 4;
#pragma unroll
        for (int r = 0; r < 4; ++r)
          out[(size_t)(rbase + r) * Nout + col] = acc[m][n][r] + bs;
      }
    }
  }
}

// ---------- flash attention: softmax(scale * q k^T) @ v  (all-validated parts) ----------
// Round-0 structure (PASSED): 4 waves x 32 q-rows, 128-row q-tiles, full KV range,
// per-iter barrier, direct normalized output. Micro-wins validated in round 4's
// passing kernel: exp2 domain, setprio, XCD swizzle, 72-short P-stride.
// NO defer-max, NO KV-split (the unvalidated combo that NaN'd in round 11).
__global__ __launch_bounds__(256) void k_attn(
    const bf16* __restrict__ q, const bf16* __restrict__ k, const bf16* __restrict__ vT,
    const float* __restrict__ scale, bf16* __restrict__ wout) {
  __shared__ short Pl_all[4][32 * 72];  // per-wave P [32 rows][72 shorts] (144B rows)
  const int tid = threadIdx.x, wid = tid >> 6, lane = tid & 63;
  const int hi = lane >> 4, lo = lane & 15;
  short* Pl = &Pl_all[wid][0];

  const int bid = blockIdx.x;                 // grid 512
  const int nid = (bid & 7) * 64 + (bid >> 3);  // bijective XCD swizzle (512 % 8 == 0)
  const int bh = nid >> 4;                    // 0..31 (4 consecutive bh per XCD)
  const int qt = nid & 15;                    // q-tile (128 rows)
  const int b = bh >> 4, h = bh & 15;
  const bf16* qp = q + (size_t)bh * kN * kHd;
  const bf16* kp = k + (size_t)bh * kN * kHd;
  const bf16* vp = vT + (size_t)bh * kHd * kN;
  const float sc2 = scale[bh] * kLog2e;  // base-2 softmax domain
  const int qb = qt * 128 + wid * 32;

  short8 aq[2][2];  // Q frags hoisted: [m-frag][k-step]
#pragma unroll
  for (int m = 0; m < 2; ++m)
#pragma unroll
    for (int ks = 0; ks < 2; ++ks)
      aq[m][ks] = *(const short8*)(qp + (size_t)(qb + m * 16 + lo) * kHd + ks * 32 + hi * 8);

  f32x4 oacc[2][4] = {};
  float runm[2][4], lsum[2][4];
#pragma unroll
  for (int m = 0; m < 2; ++m)
#pragma unroll
    for (int r = 0; r < 4; ++r) { runm[m][r] = -1e30f; lsum[m][r] = 0.f; }

  for (int t = 0; t < kN / 64; ++t) {
    __syncthreads();  // keep waves in phase for K/V L1 reuse
    const int kv0 = t * 64;
    f32x4 sacc[2][4] = {};
#pragma unroll
    for (int ks = 0; ks < 2; ++ks) {
      short8 kf[4];
#pragma unroll
      for (int j = 0; j < 4; ++j)
        kf[j] = *(const short8*)(kp + (size_t)(kv0 + j * 16 + lo) * kHd + ks * 32 + hi * 8);
      __builtin_amdgcn_s_setprio(1);
#pragma unroll
      for (int m = 0; m < 2; ++m)
#pragma unroll
        for (int j = 0; j < 4; ++j)
          sacc[m][j] = MFMA_BF16(aq[m][ks], kf[j], sacc[m][j]);
      __builtin_amdgcn_s_setprio(0);
    }

    // online softmax (always-rescale, round-0 algebra in exp2 domain)
    // C/D layout: row = m*16 + hi*4 + r (q), col = j*16 + lo (kv)
#pragma unroll
    for (int m = 0; m < 2; ++m)
#pragma unroll
      for (int r = 0; r < 4; ++r) {
        float mx = fmaxf(fmaxf(sacc[m][0][r], sacc[m][1][r]),
                         fmaxf(sacc[m][2][r], sacc[m][3][r]));
        mx *= sc2;  // sc2 > 0: max commutes with scaling
#pragma unroll
        for (int off = 1; off < 16; off <<= 1) mx = fmaxf(mx, __shfl_xor(mx, off));
        const float nm = fmaxf(runm[m][r], mx);
        const float corr = exp2f(runm[m][r] - nm);
        runm[m][r] = nm;
        float p[4], rs = 0.f;
#pragma unroll
        for (int j = 0; j < 4; ++j) {
          p[j] = exp2f(sacc[m][j][r] * sc2 - nm);
          rs += p[j];
        }
#pragma unroll
        for (int off = 1; off < 16; off <<= 1) rs += __shfl_xor(rs, off);
        lsum[m][r] = lsum[m][r] * corr + rs;
#pragma unroll
        for (int jd = 0; jd < 4; ++jd) oacc[m][jd][r] *= corr;
#pragma unroll
        for (int j = 0; j < 4; ++j)
          Pl[(m * 16 + hi * 4 + r) * 72 + j * 16 + lo] = f2bfbits(p[j]);
      }

    // PV: A-frag from P-LDS (row=lo), B-frag contiguous from vT
#pragma unroll
    for (int ks = 0; ks < 2; ++ks) {
      short8 pf[2], vf[4];
#pragma unroll
      for (int m = 0; m < 2; ++m)
        pf[m] = *(const short8*)(Pl + (m * 16 + lo) * 72 + ks * 32 + hi * 8);
#pragma unroll
      for (int jd = 0; jd < 4; ++jd)
        vf[jd] = *(const short8*)(vp + (size_t)(jd * 16 + lo) * kN + kv0 + ks * 32 + hi * 8);
      __builtin_amdgcn_s_setprio(1);
#pragma unroll
      for (int m = 0; m < 2; ++m)
#pragma unroll
        for (int jd = 0; jd < 4; ++jd)
          oacc[m][jd] = MFMA_BF16(pf[m], vf[jd], oacc[m][jd]);
      __builtin_amdgcn_s_setprio(0);
    }
  }

#pragma unroll
  for (int m = 0; m < 2; ++m)
#pragma unroll
    for (int jd = 0; jd < 4; ++jd)
#pragma unroll
      for (int r = 0; r < 4; ++r) {
        int n = qb + m * 16 + hi * 4 + r;
        float val = oacc[m][jd][r] / lsum[m][r];
        wout[((size_t)b * kN + n) * kD + h * kHd + jd * 16 + lo] = __float2bfloat16(val);
      }
}

extern "C" void kernel_launch(void* const* d_in, const int* in_sizes, int n_in,
                              void* d_out, int out_size, void* d_ws, size_t ws_size,
                              hipStream_t stream) {
  const float* x     = (const float*)d_in[0];
  const float* Wqkv  = (const float*)d_in[1];
  const float* bqkv  = (const float*)d_in[2];
  const float* Wproj = (const float*)d_in[3];
  const float* bproj = (const float*)d_in[4];
  float* out = (float*)d_out;

  char* ws = (char*)d_ws;
  size_t off = 0;
  auto alloc = [&](size_t bytes) {
    char* p = ws + off;
    off = (off + bytes + 255) & ~(size_t)255;
    return p;
  };
  bf16* xb   = (bf16*)alloc((size_t)kB * kN * kD * 2);        // 16 MB
  bf16* WqT  = (bf16*)alloc((size_t)3 * kD * kD * 2);         // 6 MB  [3D][D]
  bf16* WpT  = (bf16*)alloc((size_t)kD * kD * 2);             // 2 MB  [D][D]
  bf16* qd   = (bf16*)alloc((size_t)kB * kH * kN * kHd * 2);  // 8 MB  [BH][N][hd]
  bf16* kd   = (bf16*)alloc((size_t)kB * kH * kN * kHd * 2);  // 8 MB
  bf16* vTd  = (bf16*)alloc((size_t)kB * kH * kHd * kN * 2);  // 8 MB  [BH][hd][N]
  bf16* wo   = (bf16*)alloc((size_t)kB * kN * kD * 2);        // 8 MB  [B][N][D]
  float* colsum = (float*)alloc((size_t)kB * kD * 4);         // 8192 B
  float* froqsq = (float*)alloc((size_t)kB * kH * 4);         // at colsum+8192
  float* scl    = (float*)alloc((size_t)kB * kH * 4);

  // zero colsum (8192 B) + froqsq slot (256 B reserved) in one memset
  hipMemsetAsync(colsum, 0, (size_t)kB * kD * 4 + 256, stream);

  k_convert<<<dim3(kB * kN * kD / 4 / 256), 256, 0, stream>>>(x, xb, kB * kN * kD / 4);
  k_transpose<<<dim3(3 * kD / 32, kD / 32), 256, 0, stream>>>(Wqkv, WqT, kD, 3 * kD);
  k_transpose<<<dim3(kD / 32, kD / 32), 256, 0, stream>>>(Wproj, WpT, kD, kD);
  k_colsum<<<dim3(kD / 256, kN / 256, kB), 256, 0, stream>>>(x, colsum);

  k_gemm<0, 24><<<dim3(24 * 32), 256, 0, stream>>>(
      xb, WqT, bqkv, kD, 3 * kD, qd, kd, vTd, nullptr);

  k_froq<<<dim3(kB * kH, 8), 256, 0, stream>>>(qd, froqsq);
  k_scale<<<1, 256, 0, stream>>>(colsum, froqsq, scl);

  k_attn<<<dim3(512), 256, 0, stream>>>(qd, kd, vTd, scl, wo);

  k_gemm<1, 8><<<dim3(8 * 32), 256, 0, stream>>>(
      wo, WpT, bproj, kD, kD, nullptr, nullptr, nullptr, out);
}